// Round 6
// baseline (150.959 us; speedup 1.0000x reference)
//
#include <hip/hip_runtime.h>

#define S_LEN 2048
#define NH 32
#define NKV 8
#define HD 128
#define WINDOW 1024
#define NEG_INF_F -1e30f
// -log2(10000)/64
#define NEG_L2_10K_O64 -0.2076205059304601f
#define LOG2E_F 1.442695040888963f

typedef unsigned short ushort_t;
typedef __attribute__((ext_vector_type(8))) short short8;
typedef __attribute__((ext_vector_type(4))) float floatx4;
typedef __attribute__((ext_vector_type(16))) float floatx16;
typedef __attribute__((ext_vector_type(4))) int intx4;

static __device__ __forceinline__ float fexp2(float x) {
  return __builtin_amdgcn_exp2f(x);
}

static __device__ __forceinline__ ushort_t f2bf(float f) {
  union { float f; unsigned u; } un; un.f = f;
  unsigned r = un.u + 0x7fffu + ((un.u >> 16) & 1u);
  return (ushort_t)(r >> 16);
}

// half-up-round packed bf16 (P only; P>=0): 2 v_add + 1 v_perm
static __device__ __forceinline__ unsigned packP(float a, float b) {
  unsigned ua = __builtin_bit_cast(unsigned, a) + 0x8000u;
  unsigned ub = __builtin_bit_cast(unsigned, b) + 0x8000u;
  return __builtin_amdgcn_perm(ub, ua, 0x07060302u);  // [b_hi16 : a_hi16]
}

// ---------------- pre-pass: RoPE K / cast V into FRAGMENT-CONTIGUOUS layouts.
// Kr2[(kv*64+kblk)*4096 + t*512 + lane*8 + j] = Krope[key=kblk*32+(lane&31)]
//                                                    [d = t*16 + (lane>>5)*8 + j]
// Vt2[(kv*128+khalf)*2048 + tl*512 + lane*8 + j] = V[key=khalf*16+(lane>>5)*8+j]
//                                                   [d = tl*32 + (lane&31)]
// grid = 8 kv * 32 s-blocks of 64 rows
__global__ __launch_bounds__(256) void prep_kv(
    const float* __restrict__ k, const float* __restrict__ v,
    const int* __restrict__ positions, ushort_t* __restrict__ Kr2,
    ushort_t* __restrict__ Vt2) {
  __shared__ __align__(16) ushort_t lt[64 * 136];
  const int kv = blockIdx.x & 7;
  const int s0 = (blockIdx.x >> 3) * 64;
  const int tid = threadIdx.x;

  // --- K phase: RoPE -> LDS (bf16)
  {
    const int i = tid & 63;
    const int wrow = tid >> 6;
    const float invf = fexp2((float)i * NEG_L2_10K_O64);
#pragma unroll 4
    for (int it = 0; it < 16; ++it) {
      int row = it * 4 + wrow;
      int s = s0 + row;
      float pos = (float)positions[s];
      const float* kp = k + ((size_t)s * NKV + kv) * HD;
      float x1 = kp[i], x2 = kp[i + 64];
      float sn, cs;
      __sincosf(pos * invf, &sn, &cs);
      lt[row * 136 + i] = f2bf(x1 * cs - x2 * sn);
      lt[row * 136 + i + 64] = f2bf(x2 * cs + x1 * sn);
    }
  }
  __syncthreads();
  // K fragment write (coalesced 16B stores)
#pragma unroll
  for (int it = 0; it < 4; ++it) {
    int slot = it * 256 + tid;
    int kb_l = slot >> 9;
    int rem = slot & 511;
    int t = rem >> 6;
    int lane = rem & 63;
    int key_l = kb_l * 32 + (lane & 31);
    int dbase = t * 16 + (lane >> 5) * 8;
    short8 val = *(const short8*)&lt[key_l * 136 + dbase];
    *(short8*)&Kr2[(size_t)(kv * 64 + (s0 >> 5) + kb_l) * 4096 + t * 512 + lane * 8] = val;
  }
  __syncthreads();
  // --- V phase: cast -> LDS
  {
    const int d = tid & 127;
    const int r2 = tid >> 7;
#pragma unroll
    for (int it = 0; it < 32; ++it) {
      int row = it * 2 + r2;
      lt[row * 136 + d] = f2bf(v[((size_t)(s0 + row) * NKV + kv) * HD + d]);
    }
  }
  __syncthreads();
  // V fragment write
#pragma unroll
  for (int it = 0; it < 4; ++it) {
    int slot = it * 256 + tid;
    int kh_l = slot >> 8;
    int rem = slot & 255;
    int tl = rem >> 6;
    int lane = rem & 63;
    int d = tl * 32 + (lane & 31);
    int key0 = kh_l * 16 + (lane >> 5) * 8;
    unsigned w0 = (unsigned)lt[(key0 + 0) * 136 + d] | ((unsigned)lt[(key0 + 1) * 136 + d] << 16);
    unsigned w1 = (unsigned)lt[(key0 + 2) * 136 + d] | ((unsigned)lt[(key0 + 3) * 136 + d] << 16);
    unsigned w2 = (unsigned)lt[(key0 + 4) * 136 + d] | ((unsigned)lt[(key0 + 5) * 136 + d] << 16);
    unsigned w3 = (unsigned)lt[(key0 + 6) * 136 + d] | ((unsigned)lt[(key0 + 7) * 136 + d] << 16);
    intx4 val = {(int)w0, (int)w1, (int)w2, (int)w3};
    *(intx4*)&Vt2[(size_t)(kv * 128 + (s0 >> 4) + kh_l) * 2048 + tl * 512 + lane * 8] = val;
  }
}

// ---------------- main flash attention kernel — direct-from-L2 fragments, no K/V LDS,
// no barriers in the chunk loop. block = 4 waves: wave w = (hp = w&1, kw = w>>1).
// Wave handles head-pair hp (2 heads x 16 queries = 32 MFMA cols) for chunks ci≡kw (mod 2).
// grid = 768: per kv, 64 full tiles + 32 ramp-pair blocks -> equal work, 3 blocks/CU.
__global__ __launch_bounds__(256, 3) void attn_kernel(
    const float* __restrict__ q, const int* __restrict__ positions,
    const float* __restrict__ sinks, const ushort_t* __restrict__ Kr2,
    const ushort_t* __restrict__ Vt2, float* __restrict__ out) {
  // 40 KB: Q B-frag regions [hp][t][lane][8] (16 KB) ; epilogue O-combine (35 KB, reused)
  __shared__ __align__(16) ushort_t smem[20480];
  __shared__ float lsx[64];

  const int tid = threadIdx.x;
  const int w = tid >> 6;
  const int lane = tid & 63;
  const int u = lane >> 5;        // lane half
  const int l15 = lane & 15;
  const int hp = w & 1;
  const int kw = w >> 1;
  const int kv = blockIdx.x & 7;  // XCD-affine: this kv's K/V fragments stay in one L2
  const int bid = blockIdx.x >> 3;
  const int h = kv * 4 + hp * 2 + ((lane >> 4) & 1);
  const float QSCALE = (float)(0.08838834764831845 * 1.4426950408889634);

  const ushort_t* KbL = Kr2 + (size_t)kv * 64 * 4096 + lane * 8;
  const ushort_t* VbL = Vt2 + (size_t)kv * 128 * 2048 + lane * 8;

  int tiles[2];
  int ntiles;
  if (bid < 64) { tiles[0] = bid + 64; tiles[1] = 0; ntiles = 1; }
  else          { tiles[0] = bid - 64; tiles[1] = 127 - bid; ntiles = 2; }

  for (int ti = 0; ti < ntiles; ++ti) {
    const int q0 = tiles[ti] * 16;

    // ---- Q RoPE (+SCALE*log2e) into LDS B-frag layout; wave w stages head kv*4+w
    {
      const int hh = w;                       // head index within kv group
      const int rbase = (hh >> 1) * 4096;     // destination hp region
      const int i = lane;                     // freq index
      const float invf = fexp2((float)i * NEG_L2_10K_O64);
      const int t1 = i >> 4;
      const int j = i & 7;
      const int lhalf = ((i >> 3) & 1) * 32 + (hh & 1) * 16;
#pragma unroll 4
      for (int row = 0; row < 16; ++row) {
        float pos = (float)positions[q0 + row];
        const float* qp = q + ((size_t)(q0 + row) * NH + kv * 4 + hh) * HD;
        float x1 = qp[i], x2 = qp[i + 64];
        float sn, cs;
        __sincosf(pos * invf, &sn, &cs);
        int ldst = rbase + (lhalf + row) * 8 + j;
        smem[ldst + t1 * 512] = f2bf((x1 * cs - x2 * sn) * QSCALE);
        smem[ldst + (t1 + 4) * 512] = f2bf((x2 * cs + x1 * sn) * QSCALE);
      }
    }
    __syncthreads();

    floatx16 O[4];
#pragma unroll
    for (int i = 0; i < 4; ++i)
#pragma unroll
      for (int e = 0; e < 16; ++e) O[i][e] = 0.f;
    float lsum = 0.f;

    const int cbeg = (q0 > 1023) ? ((q0 - 1023) >> 5) : 0;
    const int cend = (q0 + 15) >> 5;
    const ushort_t* Qreg = smem + hp * 4096 + lane * 8;
    const int qp_ = q0 + l15;

    for (int ci = cbeg + kw; ci <= cend; ci += 2) {
      const int koff = ci * 32;

      // K fragments direct from L2 (each load: 64 lanes x 16B = 1 KB contiguous)
      const ushort_t* kfp = KbL + (size_t)ci * 4096;
      short8 kf[8];
#pragma unroll
      for (int t = 0; t < 8; ++t) kf[t] = *(const short8*)(kfp + t * 512);

      // S^T = K . Q^T  (M=32 keys, N=32 cols=2h*16q, K-dim=16 per MFMA)
      floatx16 C;
#pragma unroll
      for (int e = 0; e < 16; ++e) C[e] = 0.f;
#pragma unroll
      for (int t = 0; t < 8; ++t) {
        short8 qt = *(const short8*)(Qreg + t * 512);
        C = __builtin_amdgcn_mfma_f32_32x32x16_bf16(kf[t], qt, C, 0, 0, 0);
      }

      // V fragments (issued now; latency covered by exp/pack/shfl below)
      const ushort_t* vfp = VbL + (size_t)(ci * 2) * 2048;
      short8 vf[8];
#pragma unroll
      for (int tl = 0; tl < 4; ++tl) {
        vf[tl * 2 + 0] = *(const short8*)(vfp + tl * 512);
        vf[tl * 2 + 1] = *(const short8*)(vfp + 2048 + tl * 512);
      }

      // window/causal mask on edge chunks only (wave-uniform branch)
      if (koff + 31 > q0 || koff < q0 - 1008) {
#pragma unroll
        for (int ri = 0; ri < 16; ++ri) {
          int key = koff + (ri & 3) + 8 * (ri >> 2) + 4 * u;
          bool ok = (key <= qp_) && (qp_ - key < WINDOW);
          if (!ok) C[ri] = NEG_INF_F;
        }
      }

      // p = 2^score (scores pre-scaled by log2e; bounded, no max-shift needed)
#pragma unroll
      for (int ri = 0; ri < 16; ++ri) C[ri] = fexp2(C[ri]);
      float s0a = (C[0] + C[1]) + (C[2] + C[3]);
      float s0b = (C[4] + C[5]) + (C[6] + C[7]);
      float s1a = (C[8] + C[9]) + (C[10] + C[11]);
      float s1b = (C[12] + C[13]) + (C[14] + C[15]);
      lsum += (s0a + s0b) + (s1a + s1b);

      // P (C-layout) -> PV B-frags: pack pairs, exchange lane halves, select
      unsigned q01 = packP(C[0], C[1]), q23 = packP(C[2], C[3]);
      unsigned q45 = packP(C[4], C[5]), q67 = packP(C[6], C[7]);
      unsigned r01 = packP(C[8], C[9]), r23 = packP(C[10], C[11]);
      unsigned r45 = packP(C[12], C[13]), r67 = packP(C[14], C[15]);
      unsigned e01 = __shfl_xor((int)q01, 32), e23 = __shfl_xor((int)q23, 32);
      unsigned e45 = __shfl_xor((int)q45, 32), e67 = __shfl_xor((int)q67, 32);
      unsigned f01 = __shfl_xor((int)r01, 32), f23 = __shfl_xor((int)r23, 32);
      unsigned f45 = __shfl_xor((int)r45, 32), f67 = __shfl_xor((int)r67, 32);
      intx4 b0v = {(int)(u ? e45 : q01), (int)(u ? e67 : q23),
                   (int)(u ? q45 : e01), (int)(u ? q67 : e23)};
      intx4 b1v = {(int)(u ? f45 : r01), (int)(u ? f67 : r23),
                   (int)(u ? r45 : f01), (int)(u ? r67 : f23)};
      short8 bh0 = __builtin_bit_cast(short8, b0v);
      short8 bh1 = __builtin_bit_cast(short8, b1v);

      // O^T += V^T . P^T  (two 16-key halves per 32-d tile)
#pragma unroll
      for (int tl = 0; tl < 4; ++tl) {
        O[tl] = __builtin_amdgcn_mfma_f32_32x32x16_bf16(vf[tl * 2 + 0], bh0, O[tl], 0, 0, 0);
        O[tl] = __builtin_amdgcn_mfma_f32_32x32x16_bf16(vf[tl * 2 + 1], bh1, O[tl], 0, 0, 0);
      }
    }

    // RACE FIX (R5 bug): Q frags live in the same LDS bytes the epilogue reuses.
    // All waves must finish their chunk loop (which re-reads Q from LDS every
    // iteration) before kw=1 overwrites the region with O-partials.
    __syncthreads();

    // ---- epilogue: combine kw partials via LDS, normalize, store
    lsum += __shfl_xor(lsum, 32);
    float* Ef = (float*)smem;
    const int efb = hp * 4352 + lane * 68;
    if (kw == 1) {
#pragma unroll
      for (int tl = 0; tl < 4; ++tl)
#pragma unroll
        for (int g = 0; g < 4; ++g)
          *(floatx4*)&Ef[efb + tl * 16 + g * 4] =
              (floatx4){O[tl][4 * g], O[tl][4 * g + 1], O[tl][4 * g + 2], O[tl][4 * g + 3]};
      if (lane < 32) lsx[hp * 32 + lane] = lsum;
    }
    __syncthreads();
    if (kw == 0) {
      float den = lsum + lsx[hp * 32 + (lane & 31)] + fexp2(sinks[h] * LOG2E_F);
      float rl = 1.0f / den;
      float* op = out + ((size_t)(q0 + l15) * NH + h) * HD;
#pragma unroll
      for (int tl = 0; tl < 4; ++tl)
#pragma unroll
        for (int g = 0; g < 4; ++g) {
          floatx4 pv = *(const floatx4*)&Ef[efb + tl * 16 + g * 4];
          floatx4 vv;
#pragma unroll
          for (int e = 0; e < 4; ++e) vv[e] = (O[tl][4 * g + e] + pv[e]) * rl;
          *(floatx4*)(op + tl * 32 + g * 8 + 4 * u) = vv;
        }
    }
    __syncthreads();   // smem free for next tile's Q staging
  }
}

extern "C" void kernel_launch(void* const* d_in, const int* in_sizes, int n_in,
                              void* d_out, int out_size, void* d_ws, size_t ws_size,
                              hipStream_t stream) {
  const float* q = (const float*)d_in[0];
  const float* k = (const float*)d_in[1];
  const float* v = (const float*)d_in[2];
  const int* positions = (const int*)d_in[3];
  const float* sinks = (const float*)d_in[4];
  float* out = (float*)d_out;

  ushort_t* Kr2 = (ushort_t*)d_ws;                    // 4 MB fragment layout
  ushort_t* Vt2 = Kr2 + (size_t)NKV * S_LEN * HD;     // 4 MB fragment layout

  prep_kv<<<NKV * (S_LEN / 64), 256, 0, stream>>>(k, v, positions, Kr2, Vt2);
  attn_kernel<<<NKV * 96, 256, 0, stream>>>(q, positions, sinks, Kr2, Vt2, out);
}